// Round 16
// baseline (157.628 us; speedup 1.0000x reference)
//
#include <hip/hip_runtime.h>
#include <stdint.h>

// FilteredLReLU: up2(17-tap) -> *2 -> lrelu(0.01) -> down2(17-tap), fused.
// v_pk_fma_f16 SWAR with R_OUT=4: quartered per-thread latency chain,
// 4x wave count vs R14 -> maximize TLP / memory-compute overlap.
//
//   ge[m] = lrelu( sum fe[j]*x[m-4+j] ), go[m] = lrelu( sum fo[j]*x[m-3+j] )
//   z[t]  = sum de[j]*ge[t-4+j] + sum dd[j]*go[t-4+j]   (UP gain in fe/fo)

#define T_LEN 32768
#define R_OUT 4
#define TPR   (T_LEN / R_OUT)   // 8192 threads per row

typedef __fp16   cvt2 __attribute__((ext_vector_type(2)));  // pkrtz result
typedef _Float16 hpair __attribute__((ext_vector_type(2))); // arithmetic

__device__ __forceinline__ uint32_t pkrtz(float lo, float hi) {
    cvt2 p = __builtin_amdgcn_cvt_pkrtz(lo, hi);
    return __builtin_bit_cast(uint32_t, p);
}
__device__ __forceinline__ hpair h2(uint32_t u) {
    return __builtin_bit_cast(hpair, u);
}
__device__ __forceinline__ uint32_t u32(hpair h) {
    return __builtin_bit_cast(uint32_t, h);
}
__device__ __forceinline__ hpair pk_fma(hpair a, hpair b, hpair c) {
    return __builtin_elementwise_fma(a, b, c);
}
__device__ __forceinline__ hpair pk_lrelu(hpair v, hpair c01) {
    return __builtin_elementwise_max(v, v * c01);
}
__device__ __forceinline__ float lrelu(float v) { return fmaxf(v, 0.01f * v); }
__device__ __forceinline__ uint32_t rfl(uint32_t v) {
    return __builtin_amdgcn_readfirstlane(v);
}

__global__ void flrelu_pk4(
    const float* __restrict__ x,
    const float* __restrict__ up,
    const float* __restrict__ dn,
    float* __restrict__ out)
{
    const int gid = blockIdx.x * 256 + threadIdx.x;
    const int row = gid >> 13;                 // / TPR
    const int t   = (gid & (TPR - 1)) * R_OUT;
    const float* __restrict__ xrow = x + (size_t)row * T_LEN;
    float* __restrict__ orow       = out + (size_t)row * T_LEN;

    // f32 taps (uniform). UP gain folded into fe/fo.
    float fe[9], fo[8], de[9], dd[8];
    #pragma unroll
    for (int j = 0; j < 9; ++j) { fe[j] = 2.0f * up[2*j]; de[j] = dn[2*j]; }
    #pragma unroll
    for (int j = 0; j < 8; ++j) { fo[j] = 2.0f * up[2*j+1]; dd[j] = dn[2*j+1]; }

    if (t >= 8 && t + R_OUT + 8 <= T_LEN) {
        // -------- interior: packed f16 SWAR path --------
        hpair feB[9], foB[8], deB[9], ddB[8];
        #pragma unroll
        for (int j = 0; j < 9; ++j) {
            feB[j] = h2(rfl(pkrtz(fe[j], fe[j])));
            deB[j] = h2(rfl(pkrtz(de[j], de[j])));
        }
        #pragma unroll
        for (int j = 0; j < 8; ++j) {
            foB[j] = h2(rfl(pkrtz(fo[j], fo[j])));
            ddB[j] = h2(rfl(pkrtz(dd[j], dd[j])));
        }
        const hpair c01 = h2(pkrtz(0.01f, 0.01f));

        // load x[t-8 .. t+11]  (5 aligned float4)
        float xv[20];
        const float4* xp = reinterpret_cast<const float4*>(xrow + t - 8);
        #pragma unroll
        for (int k = 0; k < 5; ++k) {
            float4 v = xp[k];
            xv[4*k+0] = v.x; xv[4*k+1] = v.y;
            xv[4*k+2] = v.z; xv[4*k+3] = v.w;
        }

        // f16 pairs: aligned xa[k]=(xv[2k],xv[2k+1]); shifted xs[k]=(xv[2k+1],xv[2k+2])
        uint32_t xau[10], xsu[9];
        #pragma unroll
        for (int k = 0; k < 10; ++k) xau[k] = pkrtz(xv[2*k], xv[2*k+1]);
        #pragma unroll
        for (int k = 0; k < 9; ++k)
            xsu[k] = (xau[k] >> 16) | (xau[k+1] << 16);   // v_alignbit_b32

        // intermediate pairs ga[q]=(ge[t-4+2q], ge[t-4+2q+1]), q=0..5; same for go
        hpair ga[6], goa[6];
        #pragma unroll
        for (int q = 0; q < 6; ++q) {
            hpair s = feB[0] * h2(xau[q]);
            #pragma unroll
            for (int a = 1; a < 5; ++a) s = pk_fma(feB[2*a], h2(xau[q+a]), s);
            #pragma unroll
            for (int a = 0; a < 4; ++a) s = pk_fma(feB[2*a+1], h2(xsu[q+a]), s);
            ga[q] = pk_lrelu(s, c01);

            hpair r = foB[0] * h2(xsu[q]);
            #pragma unroll
            for (int a = 1; a < 4; ++a) r = pk_fma(foB[2*a], h2(xsu[q+a]), r);
            #pragma unroll
            for (int a = 0; a < 4; ++a) r = pk_fma(foB[2*a+1], h2(xau[q+a+1]), r);
            goa[q] = pk_lrelu(r, c01);
        }

        // shifted pairs
        hpair gs[5], gos[5];
        #pragma unroll
        for (int q = 0; q < 5; ++q) {
            gs[q]  = h2((u32(ga[q])  >> 16) | (u32(ga[q+1])  << 16));
            gos[q] = h2((u32(goa[q]) >> 16) | (u32(goa[q+1]) << 16));
        }

        // scatter: zp[p] = (z[t+2p], z[t+2p+1]), p=0..1
        hpair zp[2];
        #pragma unroll
        for (int p = 0; p < 2; ++p) {
            hpair s = deB[0] * ga[p];
            #pragma unroll
            for (int a = 1; a < 5; ++a) s = pk_fma(deB[2*a], ga[p+a], s);
            #pragma unroll
            for (int a = 0; a < 4; ++a) s = pk_fma(deB[2*a+1], gs[p+a], s);
            #pragma unroll
            for (int a = 0; a < 4; ++a) s = pk_fma(ddB[2*a], goa[p+a], s);
            #pragma unroll
            for (int a = 0; a < 4; ++a) s = pk_fma(ddB[2*a+1], gos[p+a], s);
            zp[p] = s;
        }

        *reinterpret_cast<float4*>(orow + t) =
            make_float4((float)zp[0][0], (float)zp[0][1],
                        (float)zp[1][0], (float)zp[1][1]);
    } else {
        // -------- scalar f32 boundary path --------
        float xv[R_OUT + 16];
        #pragma unroll
        for (int i = 0; i < R_OUT + 16; ++i) {
            int g = t - 8 + i;
            xv[i] = (g >= 0 && g < T_LEN) ? xrow[g] : 0.0f;
        }
        float acc[R_OUT];
        #pragma unroll
        for (int r = 0; r < R_OUT; ++r) acc[r] = 0.0f;

        #pragma unroll
        for (int ml = 0; ml < R_OUT + 8; ++ml) {
            float ae = 0.0f;
            #pragma unroll
            for (int j = 0; j < 9; ++j) ae = fmaf(fe[j], xv[ml+j], ae);
            float g = lrelu(ae);
            int m = t - 4 + ml;
            if (m < 0 || m >= T_LEN) g = 0.0f;   // dn conv zero-pads y
            #pragma unroll
            for (int r = 0; r < R_OUT; ++r)
                if (r >= ml - 8 && r <= ml)
                    acc[r] = fmaf(de[ml-r], g, acc[r]);

            if (ml < R_OUT + 7) {
                float ao = 0.0f;
                #pragma unroll
                for (int j = 0; j < 8; ++j) ao = fmaf(fo[j], xv[ml+1+j], ao);
                float h = lrelu(ao);
                if (m < 0 || m >= T_LEN) h = 0.0f;
                #pragma unroll
                for (int r = 0; r < R_OUT; ++r)
                    if (r >= ml - 7 && r <= ml)
                        acc[r] = fmaf(dd[ml-r], h, acc[r]);
            }
        }

        *reinterpret_cast<float4*>(orow + t) =
            make_float4(acc[0], acc[1], acc[2], acc[3]);
    }
}

extern "C" void kernel_launch(void* const* d_in, const int* in_sizes, int n_in,
                              void* d_out, int out_size, void* d_ws, size_t ws_size,
                              hipStream_t stream) {
    const float* x  = (const float*)d_in[0];
    const float* up = (const float*)d_in[1];
    const float* dn = (const float*)d_in[2];
    float* out      = (float*)d_out;

    const int rows    = in_sizes[0] / T_LEN;         // 2048
    const int threads = rows * TPR;                  // 16.8M
    flrelu_pk4<<<threads / 256, 256, 0, stream>>>(x, up, dn, out);
}

// Round 17
// 118.685 us; speedup vs baseline: 1.3281x; 1.3281x over previous
//
#include <hip/hip_runtime.h>
#include <stdint.h>

// FilteredLReLU: up2(17-tap) -> *2 -> lrelu(0.01) -> down2(17-tap), fused.
// R15 pk_fma SWAR (R_OUT=8) + tap-preamble hoisted to a setup kernel:
// 34 broadcast f16-pair tap words precomputed once into d_ws; main kernel
// reads them via uniform s_loads (zero VALU) -> ~26% fewer VALU ops/thread.
//
//   ge[m] = lrelu( sum fe[j]*x[m-4+j] ), go[m] = lrelu( sum fo[j]*x[m-3+j] )
//   z[t]  = sum de[j]*ge[t-4+j] + sum dd[j]*go[t-4+j]   (UP gain in fe/fo)

#define T_LEN 32768
#define R_OUT 8
#define TPR   (T_LEN / R_OUT)   // 4096 threads per row

typedef __fp16   cvt2 __attribute__((ext_vector_type(2)));  // pkrtz result
typedef _Float16 hpair __attribute__((ext_vector_type(2))); // arithmetic

__device__ __forceinline__ uint32_t pkrtz(float lo, float hi) {
    cvt2 p = __builtin_amdgcn_cvt_pkrtz(lo, hi);
    return __builtin_bit_cast(uint32_t, p);
}
__device__ __forceinline__ hpair h2(uint32_t u) {
    return __builtin_bit_cast(hpair, u);
}
__device__ __forceinline__ uint32_t u32(hpair h) {
    return __builtin_bit_cast(uint32_t, h);
}
__device__ __forceinline__ hpair pk_fma(hpair a, hpair b, hpair c) {
    return __builtin_elementwise_fma(a, b, c);
}
__device__ __forceinline__ hpair pk_lrelu(hpair v, hpair c01) {
    return __builtin_elementwise_max(v, v * c01);
}
__device__ __forceinline__ float lrelu(float v) { return fmaxf(v, 0.01f * v); }

// ---- setup: broadcast tap pairs once into ws[0..33] ----
// ws[0..8]=feB, ws[9..16]=foB, ws[17..25]=deB, ws[26..33]=ddB
__global__ void pack_taps(const float* __restrict__ up,
                          const float* __restrict__ dn,
                          uint32_t* __restrict__ ws) {
    if (threadIdx.x == 0 && blockIdx.x == 0) {
        #pragma unroll
        for (int j = 0; j < 9; ++j) {
            float fe = 2.0f * up[2*j];
            float de = dn[2*j];
            ws[j]      = pkrtz(fe, fe);
            ws[17 + j] = pkrtz(de, de);
        }
        #pragma unroll
        for (int j = 0; j < 8; ++j) {
            float fo = 2.0f * up[2*j+1];
            float dd = dn[2*j+1];
            ws[9 + j]  = pkrtz(fo, fo);
            ws[26 + j] = pkrtz(dd, dd);
        }
    }
}

__global__ void flrelu_pk8t(
    const float* __restrict__ x,
    const float* __restrict__ up,
    const float* __restrict__ dn,
    const uint32_t* __restrict__ tw,
    float* __restrict__ out)
{
    const int gid = blockIdx.x * 256 + threadIdx.x;
    const int row = gid >> 12;                 // / TPR
    const int t   = (gid & (TPR - 1)) * R_OUT;
    const float* __restrict__ xrow = x + (size_t)row * T_LEN;
    float* __restrict__ orow       = out + (size_t)row * T_LEN;

    if (t >= 8 && t + R_OUT + 8 <= T_LEN) {
        // -------- interior: packed f16 SWAR path --------
        // taps: uniform pointer + const idx -> s_load (no VALU)
        hpair feB[9], foB[8], deB[9], ddB[8];
        #pragma unroll
        for (int j = 0; j < 9; ++j) { feB[j] = h2(tw[j]); deB[j] = h2(tw[17+j]); }
        #pragma unroll
        for (int j = 0; j < 8; ++j) { foB[j] = h2(tw[9+j]); ddB[j] = h2(tw[26+j]); }
        const hpair c01 = h2(pkrtz(0.01f, 0.01f));

        // load x[t-8 .. t+15]  (6 aligned float4)
        float xv[24];
        const float4* xp = reinterpret_cast<const float4*>(xrow + t - 8);
        #pragma unroll
        for (int k = 0; k < 6; ++k) {
            float4 v = xp[k];
            xv[4*k+0] = v.x; xv[4*k+1] = v.y;
            xv[4*k+2] = v.z; xv[4*k+3] = v.w;
        }

        // f16 pairs: aligned xa[k]=(xv[2k],xv[2k+1]); shifted xs[k]=(xv[2k+1],xv[2k+2])
        uint32_t xau[12], xsu[11];
        #pragma unroll
        for (int k = 0; k < 12; ++k) xau[k] = pkrtz(xv[2*k], xv[2*k+1]);
        #pragma unroll
        for (int k = 0; k < 11; ++k)
            xsu[k] = (xau[k] >> 16) | (xau[k+1] << 16);   // v_alignbit_b32

        // intermediate pairs ga[q]=(ge[t-4+2q], ge[t-4+2q+1]), q=0..7; same for go
        hpair ga[8], goa[8];
        #pragma unroll
        for (int q = 0; q < 8; ++q) {
            hpair s = feB[0] * h2(xau[q]);
            #pragma unroll
            for (int a = 1; a < 5; ++a) s = pk_fma(feB[2*a], h2(xau[q+a]), s);
            #pragma unroll
            for (int a = 0; a < 4; ++a) s = pk_fma(feB[2*a+1], h2(xsu[q+a]), s);
            ga[q] = pk_lrelu(s, c01);

            hpair r = foB[0] * h2(xsu[q]);
            #pragma unroll
            for (int a = 1; a < 4; ++a) r = pk_fma(foB[2*a], h2(xsu[q+a]), r);
            #pragma unroll
            for (int a = 0; a < 4; ++a) r = pk_fma(foB[2*a+1], h2(xau[q+a+1]), r);
            goa[q] = pk_lrelu(r, c01);
        }

        // shifted pairs
        hpair gs[7], gos[7];
        #pragma unroll
        for (int q = 0; q < 7; ++q) {
            gs[q]  = h2((u32(ga[q])  >> 16) | (u32(ga[q+1])  << 16));
            gos[q] = h2((u32(goa[q]) >> 16) | (u32(goa[q+1]) << 16));
        }

        // scatter: zp[p] = (z[t+2p], z[t+2p+1]), p=0..3
        hpair zp[4];
        #pragma unroll
        for (int p = 0; p < 4; ++p) {
            hpair s = deB[0] * ga[p];
            #pragma unroll
            for (int a = 1; a < 5; ++a) s = pk_fma(deB[2*a], ga[p+a], s);
            #pragma unroll
            for (int a = 0; a < 4; ++a) s = pk_fma(deB[2*a+1], gs[p+a], s);
            #pragma unroll
            for (int a = 0; a < 4; ++a) s = pk_fma(ddB[2*a], goa[p+a], s);
            #pragma unroll
            for (int a = 0; a < 4; ++a) s = pk_fma(ddB[2*a+1], gos[p+a], s);
            zp[p] = s;
        }

        float4* op = reinterpret_cast<float4*>(orow + t);
        #pragma unroll
        for (int k = 0; k < 2; ++k)
            op[k] = make_float4((float)zp[2*k][0], (float)zp[2*k][1],
                                (float)zp[2*k+1][0], (float)zp[2*k+1][1]);
    } else {
        // -------- scalar f32 boundary path --------
        float fe[9], fo[8], de[9], dd[8];
        #pragma unroll
        for (int j = 0; j < 9; ++j) { fe[j] = 2.0f * up[2*j]; de[j] = dn[2*j]; }
        #pragma unroll
        for (int j = 0; j < 8; ++j) { fo[j] = 2.0f * up[2*j+1]; dd[j] = dn[2*j+1]; }

        float xv[R_OUT + 16];
        #pragma unroll
        for (int i = 0; i < R_OUT + 16; ++i) {
            int g = t - 8 + i;
            xv[i] = (g >= 0 && g < T_LEN) ? xrow[g] : 0.0f;
        }
        float acc[R_OUT];
        #pragma unroll
        for (int r = 0; r < R_OUT; ++r) acc[r] = 0.0f;

        #pragma unroll
        for (int ml = 0; ml < R_OUT + 8; ++ml) {
            float ae = 0.0f;
            #pragma unroll
            for (int j = 0; j < 9; ++j) ae = fmaf(fe[j], xv[ml+j], ae);
            float g = lrelu(ae);
            int m = t - 4 + ml;
            if (m < 0 || m >= T_LEN) g = 0.0f;   // dn conv zero-pads y
            #pragma unroll
            for (int r = 0; r < R_OUT; ++r)
                if (r >= ml - 8 && r <= ml)
                    acc[r] = fmaf(de[ml-r], g, acc[r]);

            if (ml < R_OUT + 7) {
                float ao = 0.0f;
                #pragma unroll
                for (int j = 0; j < 8; ++j) ao = fmaf(fo[j], xv[ml+1+j], ao);
                float h = lrelu(ao);
                if (m < 0 || m >= T_LEN) h = 0.0f;
                #pragma unroll
                for (int r = 0; r < R_OUT; ++r)
                    if (r >= ml - 7 && r <= ml)
                        acc[r] = fmaf(dd[ml-r], h, acc[r]);
            }
        }

        float4* op = reinterpret_cast<float4*>(orow + t);
        #pragma unroll
        for (int k = 0; k < R_OUT / 4; ++k)
            op[k] = make_float4(acc[4*k+0], acc[4*k+1], acc[4*k+2], acc[4*k+3]);
    }
}

extern "C" void kernel_launch(void* const* d_in, const int* in_sizes, int n_in,
                              void* d_out, int out_size, void* d_ws, size_t ws_size,
                              hipStream_t stream) {
    const float* x  = (const float*)d_in[0];
    const float* up = (const float*)d_in[1];
    const float* dn = (const float*)d_in[2];
    float* out      = (float*)d_out;
    uint32_t* ws    = (uint32_t*)d_ws;

    pack_taps<<<1, 64, 0, stream>>>(up, dn, ws);

    const int rows    = in_sizes[0] / T_LEN;         // 2048
    const int threads = rows * TPR;                  // 8.39M
    flrelu_pk8t<<<threads / 256, 256, 0, stream>>>(x, up, dn, ws, out);
}